// Round 2
// baseline (1000.486 us; speedup 1.0000x reference)
//
#include <hip/hip_runtime.h>
#include <math.h>
#include <stdint.h>

#define NLEV 16
#define TSIZE (1u << 19)
#define NB 4096
#define NS 48
#define NPTS (NB * NS)

struct Scales { float s[NLEV]; };

__device__ __forceinline__ uint32_t hash3(uint32_t x, uint32_t y, uint32_t z) {
    return (x ^ (y * 2654435761u) ^ (z * 805459861u)) & (TSIZE - 1u);
}

__device__ __forceinline__ float sigmoidf(float v) {
    return 1.0f / (1.0f + expf(-v));
}

// k0: per-point camera transform + selector; writes q as float4 (coalesced).
__global__ __launch_bounds__(256) void transform_kernel(
    const float* __restrict__ positions,
    const float* __restrict__ c2w,
    float4* __restrict__ q_ws)
{
    const int g = blockIdx.x * blockDim.x + threadIdx.x;
    if (g >= NPTS) return;
    const int b = g / NS;
    const float* M = c2w + b * 12;
    const float R00 = M[0], R01 = M[1], R02 = M[2],  T0 = M[3];
    const float R10 = M[4], R11 = M[5], R12 = M[6],  T1 = M[7];
    const float R20 = M[8], R21 = M[9], R22 = M[10], T2 = M[11];

    const float px = positions[3 * g + 0];
    const float py = positions[3 * g + 1];
    const float pz = positions[3 * g + 2];
    const float dx = px - T0, dy = py - T1, dz = pz - T2;
    float qx = R00 * dx + R10 * dy + R20 * dz;
    float qy = R01 * dx + R11 * dy + R21 * dz;
    float qz = R02 * dx + R12 * dy + R22 * dz;
    qx = (qx + 1.0f) * 0.5f;
    qy = (qy + 1.0f) * 0.5f;
    qz = (qz + 1.0f) * 0.5f;
    const bool sel = (qx > 0.0f) && (qx < 1.0f) &&
                     (qy > 0.0f) && (qy < 1.0f) &&
                     (qz > 0.0f) && (qz < 1.0f);
    if (!sel) { qx = 0.0f; qy = 0.0f; qz = 0.0f; }
    q_ws[g] = make_float4(qx, qy, qz, 0.0f);
}

// k1: one thread per (point, level). blockIdx.y = level (wave-uniform scale
// and table base). Gathers 8 corners, trilinear-interps, writes float2 to
// level-major enc_ws[l][p] (coalesced stores).
__global__ __launch_bounds__(256) void encode_kernel(
    const float4* __restrict__ q_ws,
    const float* __restrict__ table,
    float2* __restrict__ enc_ws,
    Scales sc)
{
    const int p = blockIdx.x * blockDim.x + threadIdx.x;
    if (p >= NPTS) return;
    const int l = blockIdx.y;

    const float4 q = q_ws[p];
    const float s = sc.s[l];
    const float sx = q.x * s, sy = q.y * s, sz = q.z * s;
    const float fx = floorf(sx), fy = floorf(sy), fz = floorf(sz);
    const float cx = ceilf(sx),  cy = ceilf(sy),  cz = ceilf(sz);
    const float ox = sx - fx, oy = sy - fy, oz = sz - fz;
    const uint32_t fxi = (uint32_t)fx, fyi = (uint32_t)fy, fzi = (uint32_t)fz;
    const uint32_t cxi = (uint32_t)cx, cyi = (uint32_t)cy, czi = (uint32_t)cz;

    const float2* tab2 = (const float2*)table + (uint32_t)l * TSIZE;
    const float2 f0 = tab2[hash3(cxi, cyi, czi)];
    const float2 f1 = tab2[hash3(cxi, fyi, czi)];
    const float2 f2 = tab2[hash3(fxi, fyi, czi)];
    const float2 f3 = tab2[hash3(fxi, cyi, czi)];
    const float2 f4 = tab2[hash3(cxi, cyi, fzi)];
    const float2 f5 = tab2[hash3(cxi, fyi, fzi)];
    const float2 f6 = tab2[hash3(fxi, fyi, fzi)];
    const float2 f7 = tab2[hash3(fxi, cyi, fzi)];

    const float omx = 1.0f - ox, omy = 1.0f - oy, omz = 1.0f - oz;
    float f03x = f0.x * ox + f3.x * omx, f03y = f0.y * ox + f3.y * omx;
    float f12x = f1.x * ox + f2.x * omx, f12y = f1.y * ox + f2.y * omx;
    float f56x = f5.x * ox + f6.x * omx, f56y = f5.y * ox + f6.y * omx;
    float f47x = f4.x * ox + f7.x * omx, f47y = f4.y * ox + f7.y * omx;
    float ax = f03x * oy + f12x * omy, ay = f03y * oy + f12y * omy;
    float bx = f47x * oy + f56x * omy, by = f47y * oy + f56y * omy;
    enc_ws[l * NPTS + p] = make_float2(ax * oz + bx * omz, ay * oz + by * omz);
}

// k2: per-point MLPs. enc loads are level-major (coalesced float2 per wave).
// SH16 recomputed per point (~60 FLOPs, negligible vs 9408 FMAs).
__global__ __launch_bounds__(256) void mlp_kernel(
    const float2* __restrict__ enc_ws,
    const float* __restrict__ normals,
    const float* __restrict__ c2w,
    const float* __restrict__ w1, const float* __restrict__ b1,
    const float* __restrict__ w2, const float* __restrict__ b2,
    const float* __restrict__ h1, const float* __restrict__ hb1,
    const float* __restrict__ h2, const float* __restrict__ hb2,
    const float* __restrict__ h3, const float* __restrict__ hb3,
    float* __restrict__ rgb_out)
{
    const int g = blockIdx.x * blockDim.x + threadIdx.x;
    if (g >= NPTS) return;
    const int b = g / NS;

    float enc[32];
#pragma unroll
    for (int l = 0; l < NLEV; ++l) {
        const float2 e = enc_ws[l * NPTS + g];
        enc[2 * l + 0] = e.x;
        enc[2 * l + 1] = e.y;
    }

    // ---- geo MLP: 32 -> 64 -> 16, relu ----
    float a1[64];
#pragma unroll
    for (int j = 0; j < 64; ++j) {
        float acc = b1[j];
#pragma unroll
        for (int i = 0; i < 32; ++i) acc += enc[i] * w1[i * 64 + j];
        a1[j] = fmaxf(acc, 0.0f);
    }
    float geo[16];
#pragma unroll
    for (int j = 0; j < 16; ++j) {
        float acc = b2[j];
#pragma unroll
        for (int i = 0; i < 64; ++i) acc += a1[i] * w2[i * 16 + j];
        geo[j] = fmaxf(acc, 0.0f);
    }

    // ---- SH16 ----
    float hvec[32];
    {
        const float* M = c2w + b * 12;
        const float n0 = normals[3 * b + 0];
        const float n1 = normals[3 * b + 1];
        const float n2 = normals[3 * b + 2];
        float x = M[0] * n0 + M[4] * n1 + M[8] * n2;
        float y = M[1] * n0 + M[5] * n1 + M[9] * n2;
        float z = M[2] * n0 + M[6] * n1 + M[10] * n2;
        x = (x + 1.0f) * 0.5f;
        y = (y + 1.0f) * 0.5f;
        z = (z + 1.0f) * 0.5f;
        const float xx = x * x, yy = y * y, zz = z * z;
        hvec[0]  = 0.28209479177387814f;
        hvec[1]  = -0.48860251190291987f * y;
        hvec[2]  = 0.48860251190291987f * z;
        hvec[3]  = -0.48860251190291987f * x;
        hvec[4]  = 1.0925484305920792f * x * y;
        hvec[5]  = -1.0925484305920792f * y * z;
        hvec[6]  = 0.94617469575756f * zz - 0.31539156525252f;
        hvec[7]  = -1.0925484305920792f * x * z;
        hvec[8]  = 0.5462742152960396f * (xx - yy);
        hvec[9]  = 0.5900435899266435f * y * (3.0f * xx - yy);
        hvec[10] = 2.890611442640554f * x * y * z;
        hvec[11] = 0.4570457994644657f * y * (5.0f * zz - 1.0f);
        hvec[12] = 0.37317633259011546f * z * (5.0f * zz - 3.0f);
        hvec[13] = 0.4570457994644657f * x * (5.0f * zz - 1.0f);
        hvec[14] = 1.445305721320277f * z * (xx - yy);
        hvec[15] = 0.5900435899266435f * x * (xx - 3.0f * yy);
    }
#pragma unroll
    for (int j = 0; j < 16; ++j) hvec[16 + j] = geo[j];

    // ---- rgb MLP: 32 -> 64 -> 64 -> 3, relu, sigmoid ----
    float g1[64];
#pragma unroll
    for (int j = 0; j < 64; ++j) {
        float acc = hb1[j];
#pragma unroll
        for (int i = 0; i < 32; ++i) acc += hvec[i] * h1[i * 64 + j];
        g1[j] = fmaxf(acc, 0.0f);
    }
    float g2[64];
#pragma unroll
    for (int j = 0; j < 64; ++j) {
        float acc = hb2[j];
#pragma unroll
        for (int i = 0; i < 64; ++i) acc += g1[i] * h2[i * 64 + j];
        g2[j] = fmaxf(acc, 0.0f);
    }
#pragma unroll
    for (int c = 0; c < 3; ++c) {
        float acc = hb3[c];
#pragma unroll
        for (int i = 0; i < 64; ++i) acc += g2[i] * h3[i * 3 + c];
        rgb_out[3 * g + c] = sigmoidf(acc);
    }
}

// k3: one 64-thread block per batch. Softmax over S=48, weighted rgb sum.
__global__ __launch_bounds__(64) void reduce_kernel(
    const float* __restrict__ densities,
    const float* __restrict__ rgb,
    float* __restrict__ out)
{
    const int b = blockIdx.x;
    const int t = threadIdx.x;
    const bool valid = t < NS;

    float d = valid ? densities[b * NS + t] : -INFINITY;
    float m = d;
#pragma unroll
    for (int off = 32; off > 0; off >>= 1) m = fmaxf(m, __shfl_xor(m, off));
    float e = valid ? expf(d - m) : 0.0f;
    float sum = e;
#pragma unroll
    for (int off = 32; off > 0; off >>= 1) sum += __shfl_xor(sum, off);
    const float w = e / sum;

    float r0 = 0.0f, r1 = 0.0f, r2 = 0.0f;
    if (valid) {
        const int base = (b * NS + t) * 3;
        r0 = w * rgb[base + 0];
        r1 = w * rgb[base + 1];
        r2 = w * rgb[base + 2];
    }
#pragma unroll
    for (int off = 32; off > 0; off >>= 1) {
        r0 += __shfl_xor(r0, off);
        r1 += __shfl_xor(r1, off);
        r2 += __shfl_xor(r2, off);
    }
    if (t == 0) {
        out[3 * b + 0] = r0;
        out[3 * b + 1] = r1;
        out[3 * b + 2] = r2;
    }
}

extern "C" void kernel_launch(void* const* d_in, const int* in_sizes, int n_in,
                              void* d_out, int out_size, void* d_ws, size_t ws_size,
                              hipStream_t stream) {
    const float* positions = (const float*)d_in[0];
    const float* densities = (const float*)d_in[1];
    const float* normals   = (const float*)d_in[2];
    const float* c2w       = (const float*)d_in[3];
    const float* table     = (const float*)d_in[4];
    const float* w1  = (const float*)d_in[5];
    const float* b1  = (const float*)d_in[6];
    const float* w2  = (const float*)d_in[7];
    const float* b2  = (const float*)d_in[8];
    const float* h1  = (const float*)d_in[9];
    const float* hb1 = (const float*)d_in[10];
    const float* h2  = (const float*)d_in[11];
    const float* hb2 = (const float*)d_in[12];
    const float* h3  = (const float*)d_in[13];
    const float* hb3 = (const float*)d_in[14];
    float* out = (float*)d_out;

    // ws layout: q (NPTS float4) | enc (NLEV*NPTS float2) | rgb (NPTS*3 f32)
    float4* q_ws   = (float4*)d_ws;
    float2* enc_ws = (float2*)((char*)d_ws + sizeof(float4) * NPTS);
    float*  rgb_ws = (float*)((char*)enc_ws + sizeof(float2) * NLEV * NPTS);

    Scales sc;
    const double growth = exp((log(2048.0) - log(16.0)) / 15.0);
    for (int i = 0; i < NLEV; ++i)
        sc.s[i] = (float)floor(16.0 * pow(growth, (double)i));

    const int threads = 256;
    const int pblocks = (NPTS + threads - 1) / threads;

    transform_kernel<<<pblocks, threads, 0, stream>>>(positions, c2w, q_ws);
    encode_kernel<<<dim3(pblocks, NLEV), threads, 0, stream>>>(q_ws, table, enc_ws, sc);
    mlp_kernel<<<pblocks, threads, 0, stream>>>(
        enc_ws, normals, c2w,
        w1, b1, w2, b2, h1, hb1, h2, hb2, h3, hb3, rgb_ws);
    reduce_kernel<<<NB, 64, 0, stream>>>(densities, rgb_ws, out);
}

// Round 3
// 851.929 us; speedup vs baseline: 1.1744x; 1.1744x over previous
//
#include <hip/hip_runtime.h>
#include <math.h>
#include <stdint.h>

#define NLEV 16
#define TSIZE (1u << 19)
#define NB 4096
#define NS 48
#define NPTS (NB * NS)

struct Scales { float s[NLEV]; };

__device__ __forceinline__ uint32_t hash3(uint32_t x, uint32_t y, uint32_t z) {
    return (x ^ (y * 2654435761u) ^ (z * 805459861u)) & (TSIZE - 1u);
}

__device__ __forceinline__ float sigmoidf(float v) {
    return 1.0f / (1.0f + expf(-v));
}

// k0: per-point camera transform + selector; writes q as float4 (coalesced).
__global__ __launch_bounds__(256) void transform_kernel(
    const float* __restrict__ positions,
    const float* __restrict__ c2w,
    float4* __restrict__ q_ws)
{
    const int g = blockIdx.x * blockDim.x + threadIdx.x;
    if (g >= NPTS) return;
    const int b = g / NS;
    const float* M = c2w + b * 12;
    const float R00 = M[0], R01 = M[1], R02 = M[2],  T0 = M[3];
    const float R10 = M[4], R11 = M[5], R12 = M[6],  T1 = M[7];
    const float R20 = M[8], R21 = M[9], R22 = M[10], T2 = M[11];

    const float px = positions[3 * g + 0];
    const float py = positions[3 * g + 1];
    const float pz = positions[3 * g + 2];
    const float dx = px - T0, dy = py - T1, dz = pz - T2;
    float qx = R00 * dx + R10 * dy + R20 * dz;
    float qy = R01 * dx + R11 * dy + R21 * dz;
    float qz = R02 * dx + R12 * dy + R22 * dz;
    qx = (qx + 1.0f) * 0.5f;
    qy = (qy + 1.0f) * 0.5f;
    qz = (qz + 1.0f) * 0.5f;
    const bool sel = (qx > 0.0f) && (qx < 1.0f) &&
                     (qy > 0.0f) && (qy < 1.0f) &&
                     (qz > 0.0f) && (qz < 1.0f);
    if (!sel) { qx = 0.0f; qy = 0.0f; qz = 0.0f; }
    q_ws[g] = make_float4(qx, qy, qz, 0.0f);
}

// k1: one thread per (point, level). blockIdx.y = level. Gathers 8 corners,
// trilinear-interps, writes float2 to level-major enc_ws[l][p].
__global__ __launch_bounds__(256) void encode_kernel(
    const float4* __restrict__ q_ws,
    const float* __restrict__ table,
    float2* __restrict__ enc_ws,
    Scales sc)
{
    const int p = blockIdx.x * blockDim.x + threadIdx.x;
    if (p >= NPTS) return;
    const int l = blockIdx.y;

    const float4 q = q_ws[p];
    const float s = sc.s[l];
    const float sx = q.x * s, sy = q.y * s, sz = q.z * s;
    const float fx = floorf(sx), fy = floorf(sy), fz = floorf(sz);
    const float cx = ceilf(sx),  cy = ceilf(sy),  cz = ceilf(sz);
    const float ox = sx - fx, oy = sy - fy, oz = sz - fz;
    const uint32_t fxi = (uint32_t)fx, fyi = (uint32_t)fy, fzi = (uint32_t)fz;
    const uint32_t cxi = (uint32_t)cx, cyi = (uint32_t)cy, czi = (uint32_t)cz;

    const float2* tab2 = (const float2*)table + (uint32_t)l * TSIZE;
    const float2 f0 = tab2[hash3(cxi, cyi, czi)];
    const float2 f1 = tab2[hash3(cxi, fyi, czi)];
    const float2 f2 = tab2[hash3(fxi, fyi, czi)];
    const float2 f3 = tab2[hash3(fxi, cyi, czi)];
    const float2 f4 = tab2[hash3(cxi, cyi, fzi)];
    const float2 f5 = tab2[hash3(cxi, fyi, fzi)];
    const float2 f6 = tab2[hash3(fxi, fyi, fzi)];
    const float2 f7 = tab2[hash3(fxi, cyi, fzi)];

    const float omx = 1.0f - ox, omy = 1.0f - oy, omz = 1.0f - oz;
    float f03x = f0.x * ox + f3.x * omx, f03y = f0.y * ox + f3.y * omx;
    float f12x = f1.x * ox + f2.x * omx, f12y = f1.y * ox + f2.y * omx;
    float f56x = f5.x * ox + f6.x * omx, f56y = f5.y * ox + f6.y * omx;
    float f47x = f4.x * ox + f7.x * omx, f47y = f4.y * ox + f7.y * omx;
    float ax = f03x * oy + f12x * omy, ay = f03y * oy + f12y * omy;
    float bx = f47x * oy + f56x * omy, by = f47y * oy + f56y * omy;
    enc_ws[l * NPTS + p] = make_float2(ax * oz + bx * omz, ay * oz + by * omz);
}

// k2: per-point MLPs, restructured to cap live registers (~100 floats peak):
// layer-1 neurons and last-layer neurons are streamed one at a time into
// small accumulator sets so no 64-wide array is live across two layers
// except g1. __launch_bounds__(256,2) gives a 256-VGPR budget (no spills).
__global__ __launch_bounds__(256, 2) void mlp_kernel(
    const float2* __restrict__ enc_ws,
    const float* __restrict__ normals,
    const float* __restrict__ c2w,
    const float* __restrict__ w1, const float* __restrict__ b1,
    const float* __restrict__ w2, const float* __restrict__ b2,
    const float* __restrict__ h1, const float* __restrict__ hb1,
    const float* __restrict__ h2, const float* __restrict__ hb2,
    const float* __restrict__ h3, const float* __restrict__ hb3,
    float* __restrict__ rgb_out)
{
    const int g = blockIdx.x * blockDim.x + threadIdx.x;
    if (g >= NPTS) return;
    const int b = g / NS;

    float enc[32];
#pragma unroll
    for (int l = 0; l < NLEV; ++l) {
        const float2 e = enc_ws[l * NPTS + g];
        enc[2 * l + 0] = e.x;
        enc[2 * l + 1] = e.y;
    }

    // ---- geo MLP: stream a1 neurons into 16 geo accumulators ----
    float geoacc[16];
#pragma unroll
    for (int j = 0; j < 16; ++j) geoacc[j] = b2[j];
#pragma unroll
    for (int i = 0; i < 64; ++i) {
        float a = b1[i];
#pragma unroll
        for (int k = 0; k < 32; ++k) a += enc[k] * w1[k * 64 + i];
        a = fmaxf(a, 0.0f);
#pragma unroll
        for (int j = 0; j < 16; ++j) geoacc[j] += a * w2[i * 16 + j];
    }

    // ---- hvec = [SH16, relu(geoacc)] ----
    float hvec[32];
    {
        const float* M = c2w + b * 12;
        const float n0 = normals[3 * b + 0];
        const float n1 = normals[3 * b + 1];
        const float n2 = normals[3 * b + 2];
        float x = M[0] * n0 + M[4] * n1 + M[8] * n2;
        float y = M[1] * n0 + M[5] * n1 + M[9] * n2;
        float z = M[2] * n0 + M[6] * n1 + M[10] * n2;
        x = (x + 1.0f) * 0.5f;
        y = (y + 1.0f) * 0.5f;
        z = (z + 1.0f) * 0.5f;
        const float xx = x * x, yy = y * y, zz = z * z;
        hvec[0]  = 0.28209479177387814f;
        hvec[1]  = -0.48860251190291987f * y;
        hvec[2]  = 0.48860251190291987f * z;
        hvec[3]  = -0.48860251190291987f * x;
        hvec[4]  = 1.0925484305920792f * x * y;
        hvec[5]  = -1.0925484305920792f * y * z;
        hvec[6]  = 0.94617469575756f * zz - 0.31539156525252f;
        hvec[7]  = -1.0925484305920792f * x * z;
        hvec[8]  = 0.5462742152960396f * (xx - yy);
        hvec[9]  = 0.5900435899266435f * y * (3.0f * xx - yy);
        hvec[10] = 2.890611442640554f * x * y * z;
        hvec[11] = 0.4570457994644657f * y * (5.0f * zz - 1.0f);
        hvec[12] = 0.37317633259011546f * z * (5.0f * zz - 3.0f);
        hvec[13] = 0.4570457994644657f * x * (5.0f * zz - 1.0f);
        hvec[14] = 1.445305721320277f * z * (xx - yy);
        hvec[15] = 0.5900435899266435f * x * (xx - 3.0f * yy);
    }
#pragma unroll
    for (int j = 0; j < 16; ++j) hvec[16 + j] = fmaxf(geoacc[j], 0.0f);

    // ---- g1 = relu(hvec @ h1 + hb1)  (the one 64-wide live array) ----
    float g1[64];
#pragma unroll
    for (int i = 0; i < 64; ++i) {
        float a = hb1[i];
#pragma unroll
        for (int k = 0; k < 32; ++k) a += hvec[k] * h1[k * 64 + i];
        g1[i] = fmaxf(a, 0.0f);
    }

    // ---- stream g2 neurons into 3 rgb accumulators ----
    float r0 = hb3[0], r1 = hb3[1], r2 = hb3[2];
#pragma unroll
    for (int j = 0; j < 64; ++j) {
        float v = hb2[j];
#pragma unroll
        for (int i = 0; i < 64; ++i) v += g1[i] * h2[i * 64 + j];
        v = fmaxf(v, 0.0f);
        r0 += v * h3[j * 3 + 0];
        r1 += v * h3[j * 3 + 1];
        r2 += v * h3[j * 3 + 2];
    }
    rgb_out[3 * g + 0] = sigmoidf(r0);
    rgb_out[3 * g + 1] = sigmoidf(r1);
    rgb_out[3 * g + 2] = sigmoidf(r2);
}

// k3: one 64-thread block per batch. Softmax over S=48, weighted rgb sum.
__global__ __launch_bounds__(64) void reduce_kernel(
    const float* __restrict__ densities,
    const float* __restrict__ rgb,
    float* __restrict__ out)
{
    const int b = blockIdx.x;
    const int t = threadIdx.x;
    const bool valid = t < NS;

    float d = valid ? densities[b * NS + t] : -INFINITY;
    float m = d;
#pragma unroll
    for (int off = 32; off > 0; off >>= 1) m = fmaxf(m, __shfl_xor(m, off));
    float e = valid ? expf(d - m) : 0.0f;
    float sum = e;
#pragma unroll
    for (int off = 32; off > 0; off >>= 1) sum += __shfl_xor(sum, off);
    const float w = e / sum;

    float r0 = 0.0f, r1 = 0.0f, r2 = 0.0f;
    if (valid) {
        const int base = (b * NS + t) * 3;
        r0 = w * rgb[base + 0];
        r1 = w * rgb[base + 1];
        r2 = w * rgb[base + 2];
    }
#pragma unroll
    for (int off = 32; off > 0; off >>= 1) {
        r0 += __shfl_xor(r0, off);
        r1 += __shfl_xor(r1, off);
        r2 += __shfl_xor(r2, off);
    }
    if (t == 0) {
        out[3 * b + 0] = r0;
        out[3 * b + 1] = r1;
        out[3 * b + 2] = r2;
    }
}

extern "C" void kernel_launch(void* const* d_in, const int* in_sizes, int n_in,
                              void* d_out, int out_size, void* d_ws, size_t ws_size,
                              hipStream_t stream) {
    const float* positions = (const float*)d_in[0];
    const float* densities = (const float*)d_in[1];
    const float* normals   = (const float*)d_in[2];
    const float* c2w       = (const float*)d_in[3];
    const float* table     = (const float*)d_in[4];
    const float* w1  = (const float*)d_in[5];
    const float* b1  = (const float*)d_in[6];
    const float* w2  = (const float*)d_in[7];
    const float* b2  = (const float*)d_in[8];
    const float* h1  = (const float*)d_in[9];
    const float* hb1 = (const float*)d_in[10];
    const float* h2  = (const float*)d_in[11];
    const float* hb2 = (const float*)d_in[12];
    const float* h3  = (const float*)d_in[13];
    const float* hb3 = (const float*)d_in[14];
    float* out = (float*)d_out;

    // ws layout: q (NPTS float4) | enc (NLEV*NPTS float2) | rgb (NPTS*3 f32)
    float4* q_ws   = (float4*)d_ws;
    float2* enc_ws = (float2*)((char*)d_ws + sizeof(float4) * NPTS);
    float*  rgb_ws = (float*)((char*)enc_ws + sizeof(float2) * NLEV * NPTS);

    Scales sc;
    const double growth = exp((log(2048.0) - log(16.0)) / 15.0);
    for (int i = 0; i < NLEV; ++i)
        sc.s[i] = (float)floor(16.0 * pow(growth, (double)i));

    const int threads = 256;
    const int pblocks = (NPTS + threads - 1) / threads;

    transform_kernel<<<pblocks, threads, 0, stream>>>(positions, c2w, q_ws);
    encode_kernel<<<dim3(pblocks, NLEV), threads, 0, stream>>>(q_ws, table, enc_ws, sc);
    mlp_kernel<<<pblocks, threads, 0, stream>>>(
        enc_ws, normals, c2w,
        w1, b1, w2, b2, h1, hb1, h2, hb2, h3, hb3, rgb_ws);
    reduce_kernel<<<NB, 64, 0, stream>>>(densities, rgb_ws, out);
}

// Round 4
// 265.656 us; speedup vs baseline: 3.7661x; 3.2069x over previous
//
#include <hip/hip_runtime.h>
#include <math.h>
#include <stdint.h>

#define NLEV 16
#define TSIZE (1u << 19)
#define NB 4096
#define NS 48
#define NPTS (NB * NS)

typedef __attribute__((ext_vector_type(8))) short short8;
typedef __attribute__((ext_vector_type(4))) float f32x4;

struct Scales { float s[NLEV]; };

__device__ __forceinline__ uint32_t hash3(uint32_t x, uint32_t y, uint32_t z) {
    return (x ^ (y * 2654435761u) ^ (z * 805459861u)) & (TSIZE - 1u);
}

__device__ __forceinline__ float sigmoidf(float v) {
    return 1.0f / (1.0f + expf(-v));
}

// fp32 -> bf16 (round to nearest even), raw ushort bits
__device__ __forceinline__ ushort f2b(float f) {
    union { float f; uint32_t u; } v; v.f = f;
    uint32_t r = (v.u + 0x7FFFu + ((v.u >> 16) & 1u)) >> 16;
    return (ushort)r;
}

#define MFMA16(a, b, c) __builtin_amdgcn_mfma_f32_16x16x32_bf16((a), (b), (c), 0, 0, 0)

// k0: per-point camera transform + selector; writes q as float4 (coalesced).
__global__ __launch_bounds__(256) void transform_kernel(
    const float* __restrict__ positions,
    const float* __restrict__ c2w,
    float4* __restrict__ q_ws)
{
    const int g = blockIdx.x * blockDim.x + threadIdx.x;
    if (g >= NPTS) return;
    const int b = g / NS;
    const float* M = c2w + b * 12;
    const float R00 = M[0], R01 = M[1], R02 = M[2],  T0 = M[3];
    const float R10 = M[4], R11 = M[5], R12 = M[6],  T1 = M[7];
    const float R20 = M[8], R21 = M[9], R22 = M[10], T2 = M[11];

    const float px = positions[3 * g + 0];
    const float py = positions[3 * g + 1];
    const float pz = positions[3 * g + 2];
    const float dx = px - T0, dy = py - T1, dz = pz - T2;
    float qx = R00 * dx + R10 * dy + R20 * dz;
    float qy = R01 * dx + R11 * dy + R21 * dz;
    float qz = R02 * dx + R12 * dy + R22 * dz;
    qx = (qx + 1.0f) * 0.5f;
    qy = (qy + 1.0f) * 0.5f;
    qz = (qz + 1.0f) * 0.5f;
    const bool sel = (qx > 0.0f) && (qx < 1.0f) &&
                     (qy > 0.0f) && (qy < 1.0f) &&
                     (qz > 0.0f) && (qz < 1.0f);
    if (!sel) { qx = 0.0f; qy = 0.0f; qz = 0.0f; }
    q_ws[g] = make_float4(qx, qy, qz, 0.0f);
}

// k1: one thread per (point, level). blockIdx.y = level. Gathers 8 corners,
// trilinear-interps, writes float2 to level-major enc_ws[l][p].
__global__ __launch_bounds__(256) void encode_kernel(
    const float4* __restrict__ q_ws,
    const float* __restrict__ table,
    float2* __restrict__ enc_ws,
    Scales sc)
{
    const int p = blockIdx.x * blockDim.x + threadIdx.x;
    if (p >= NPTS) return;
    const int l = blockIdx.y;

    const float4 q = q_ws[p];
    const float s = sc.s[l];
    const float sx = q.x * s, sy = q.y * s, sz = q.z * s;
    const float fx = floorf(sx), fy = floorf(sy), fz = floorf(sz);
    const float cx = ceilf(sx),  cy = ceilf(sy),  cz = ceilf(sz);
    const float ox = sx - fx, oy = sy - fy, oz = sz - fz;
    const uint32_t fxi = (uint32_t)fx, fyi = (uint32_t)fy, fzi = (uint32_t)fz;
    const uint32_t cxi = (uint32_t)cx, cyi = (uint32_t)cy, czi = (uint32_t)cz;

    const float2* tab2 = (const float2*)table + (uint32_t)l * TSIZE;
    const float2 f0 = tab2[hash3(cxi, cyi, czi)];
    const float2 f1 = tab2[hash3(cxi, fyi, czi)];
    const float2 f2 = tab2[hash3(fxi, fyi, czi)];
    const float2 f3 = tab2[hash3(fxi, cyi, czi)];
    const float2 f4 = tab2[hash3(cxi, cyi, fzi)];
    const float2 f5 = tab2[hash3(cxi, fyi, fzi)];
    const float2 f6 = tab2[hash3(fxi, fyi, fzi)];
    const float2 f7 = tab2[hash3(fxi, cyi, fzi)];

    const float omx = 1.0f - ox, omy = 1.0f - oy, omz = 1.0f - oz;
    float f03x = f0.x * ox + f3.x * omx, f03y = f0.y * ox + f3.y * omx;
    float f12x = f1.x * ox + f2.x * omx, f12y = f1.y * ox + f2.y * omx;
    float f56x = f5.x * ox + f6.x * omx, f56y = f5.y * ox + f6.y * omx;
    float f47x = f4.x * ox + f7.x * omx, f47y = f4.y * ox + f7.y * omx;
    float ax = f03x * oy + f12x * omy, ay = f03y * oy + f12y * omy;
    float bx = f47x * oy + f56x * omy, by = f47y * oy + f56y * omy;
    enc_ws[l * NPTS + p] = make_float2(ax * oz + bx * omz, ay * oz + by * omz);
}

// k2: MFMA MLP. One block = 64 points, 4 waves; each wave owns a 16-point
// m-tile. Layers chained through LDS in bf16 (fp32 accumulate). Fragment
// layouts (verified, learn_hip m89/m120):
//   A: [m=lane&15][k=quad*8+j]   B: [n=lane&15][k=quad*8+j]
//   C/D: col=lane&15, row=quad*4+reg
// Act-buffer strides padded (+8 elems) so ds_read_b128 stays 16B-aligned
// and bank spread ~2-way (free). Weight cols beyond H3's 3 outputs are
// garbage-but-ignored (each output column depends only on its own B col).
__global__ __launch_bounds__(256) void mfma_mlp_kernel(
    const float2* __restrict__ enc_ws,
    const float* __restrict__ normals,
    const float* __restrict__ c2w,
    const float* __restrict__ w1, const float* __restrict__ b1,
    const float* __restrict__ w2, const float* __restrict__ b2,
    const float* __restrict__ h1, const float* __restrict__ hb1,
    const float* __restrict__ h2, const float* __restrict__ hb2,
    const float* __restrict__ h3, const float* __restrict__ hb3,
    float* __restrict__ rgb_out)
{
    __shared__ ushort sX[64 * 40];    // L1 input  (32 feats + pad)
    __shared__ ushort sA1[64 * 72];   // L1 output (64) ; reused as V (L4 out)
    __shared__ ushort sHIN[64 * 40];  // [SH16 | geo16] (+ pad)
    __shared__ ushort sU[64 * 72];    // L3 output (64)
    __shared__ ushort sWT1[64 * 40];  // W1^T  [n][k], k-pad
    __shared__ ushort sWT2[16 * 72];  // W2^T
    __shared__ ushort sHT1[64 * 40];  // H1^T
    __shared__ ushort sHT2[64 * 72];  // H2^T
    __shared__ ushort sHT3[16 * 72];  // H3^T (rows 3..15 zero)

    const int tid = threadIdx.x;
    const int p0  = blockIdx.x * 64;

    // ---- stage weights (transpose to [n][k], bf16) ----
    for (int idx = tid; idx < 64 * 32; idx += 256) {
        const int n = idx >> 5, k = idx & 31;
        sWT1[n * 40 + k] = f2b(w1[k * 64 + n]);
        sHT1[n * 40 + k] = f2b(h1[k * 64 + n]);
    }
    for (int idx = tid; idx < 16 * 64; idx += 256) {
        const int n = idx >> 6, k = idx & 63;
        sWT2[n * 72 + k] = f2b(w2[k * 16 + n]);
        sHT3[n * 72 + k] = (n < 3) ? f2b(h3[k * 3 + n]) : (ushort)0;
    }
    for (int idx = tid; idx < 64 * 64; idx += 256) {
        const int n = idx >> 6, k = idx & 63;
        sHT2[n * 72 + k] = f2b(h2[k * 64 + n]);
    }

    // ---- stage X: enc (level-major float2) -> bf16 [point][32] ----
    {
        const int pt = tid & 63;
        const int l0 = (tid >> 6) * 4;
        const int p  = p0 + pt;
#pragma unroll
        for (int l = l0; l < l0 + 4; ++l) {
            const float2 e = enc_ws[l * NPTS + p];
            sX[pt * 40 + 2 * l]     = f2b(e.x);
            sX[pt * 40 + 2 * l + 1] = f2b(e.y);
        }
    }

    // ---- stage SH16 into sHIN[:, 0:16] ----
    if (tid < 64) {
        const int p = p0 + tid;
        const int b = p / NS;
        const float* M = c2w + b * 12;
        const float n0 = normals[3 * b + 0];
        const float n1 = normals[3 * b + 1];
        const float n2 = normals[3 * b + 2];
        float x = M[0] * n0 + M[4] * n1 + M[8] * n2;
        float y = M[1] * n0 + M[5] * n1 + M[9] * n2;
        float z = M[2] * n0 + M[6] * n1 + M[10] * n2;
        x = (x + 1.0f) * 0.5f;
        y = (y + 1.0f) * 0.5f;
        z = (z + 1.0f) * 0.5f;
        const float xx = x * x, yy = y * y, zz = z * z;
        float sh[16];
        sh[0]  = 0.28209479177387814f;
        sh[1]  = -0.48860251190291987f * y;
        sh[2]  = 0.48860251190291987f * z;
        sh[3]  = -0.48860251190291987f * x;
        sh[4]  = 1.0925484305920792f * x * y;
        sh[5]  = -1.0925484305920792f * y * z;
        sh[6]  = 0.94617469575756f * zz - 0.31539156525252f;
        sh[7]  = -1.0925484305920792f * x * z;
        sh[8]  = 0.5462742152960396f * (xx - yy);
        sh[9]  = 0.5900435899266435f * y * (3.0f * xx - yy);
        sh[10] = 2.890611442640554f * x * y * z;
        sh[11] = 0.4570457994644657f * y * (5.0f * zz - 1.0f);
        sh[12] = 0.37317633259011546f * z * (5.0f * zz - 3.0f);
        sh[13] = 0.4570457994644657f * x * (5.0f * zz - 1.0f);
        sh[14] = 1.445305721320277f * z * (xx - yy);
        sh[15] = 0.5900435899266435f * x * (xx - 3.0f * yy);
#pragma unroll
        for (int i = 0; i < 16; ++i) sHIN[tid * 40 + i] = f2b(sh[i]);
    }

    // ---- per-lane biases (global loads, L2-hit) ----
    const int lane = tid & 63;
    const int wv   = tid >> 6;
    const int l15  = lane & 15;
    const int quad = lane >> 4;
    float b1v[4], hb1v[4], hb2v[4];
#pragma unroll
    for (int nt = 0; nt < 4; ++nt) {
        b1v[nt]  = b1[nt * 16 + l15];
        hb1v[nt] = hb1[nt * 16 + l15];
        hb2v[nt] = hb2[nt * 16 + l15];
    }
    const float b2v  = b2[l15];
    const float hb3v = (l15 < 3) ? hb3[l15] : 0.0f;

    __syncthreads();
    // All inter-layer deps below are intra-wave (each wave touches only its
    // own 16 rows); per-wave in-order DS handles RAW/WAR without barriers.

    const int arow = wv * 16 + l15;          // A-operand row (point in block)
    const int crow0 = wv * 16 + quad * 4;    // C-layout base row
    const f32x4 zero = {0.0f, 0.0f, 0.0f, 0.0f};

    // ---- L1: X(32) @ W1 -> 64, +b1, relu -> sA1 ----
    {
        const short8 a = *(const short8*)&sX[arow * 40 + quad * 8];
        f32x4 c[4];
#pragma unroll
        for (int nt = 0; nt < 4; ++nt) {
            const short8 bf = *(const short8*)&sWT1[(nt * 16 + l15) * 40 + quad * 8];
            c[nt] = MFMA16(a, bf, zero);
        }
#pragma unroll
        for (int nt = 0; nt < 4; ++nt)
#pragma unroll
            for (int r = 0; r < 4; ++r) {
                const float v = fmaxf(c[nt][r] + b1v[nt], 0.0f);
                sA1[(crow0 + r) * 72 + nt * 16 + l15] = f2b(v);
            }
    }

    // ---- L2: A1(64) @ W2 -> 16 geo, +b2, relu -> sHIN[:,16:32] ----
    {
        const short8 a0 = *(const short8*)&sA1[arow * 72 + quad * 8];
        const short8 a1 = *(const short8*)&sA1[arow * 72 + 32 + quad * 8];
        const short8 bb0 = *(const short8*)&sWT2[l15 * 72 + quad * 8];
        const short8 bb1 = *(const short8*)&sWT2[l15 * 72 + 32 + quad * 8];
        f32x4 c = MFMA16(a0, bb0, zero);
        c = MFMA16(a1, bb1, c);
#pragma unroll
        for (int r = 0; r < 4; ++r) {
            const float v = fmaxf(c[r] + b2v, 0.0f);
            sHIN[(crow0 + r) * 40 + 16 + l15] = f2b(v);
        }
    }

    // ---- L3: HIN(32) @ H1 -> 64, +hb1, relu -> sU ----
    {
        const short8 a = *(const short8*)&sHIN[arow * 40 + quad * 8];
        f32x4 c[4];
#pragma unroll
        for (int nt = 0; nt < 4; ++nt) {
            const short8 bf = *(const short8*)&sHT1[(nt * 16 + l15) * 40 + quad * 8];
            c[nt] = MFMA16(a, bf, zero);
        }
#pragma unroll
        for (int nt = 0; nt < 4; ++nt)
#pragma unroll
            for (int r = 0; r < 4; ++r) {
                const float v = fmaxf(c[nt][r] + hb1v[nt], 0.0f);
                sU[(crow0 + r) * 72 + nt * 16 + l15] = f2b(v);
            }
    }

    // ---- L4: U(64) @ H2 -> 64, +hb2, relu -> sA1 (reused as V) ----
    {
        const short8 a0 = *(const short8*)&sU[arow * 72 + quad * 8];
        const short8 a1 = *(const short8*)&sU[arow * 72 + 32 + quad * 8];
        f32x4 c[4];
#pragma unroll
        for (int nt = 0; nt < 4; ++nt) {
            const short8 bb0 = *(const short8*)&sHT2[(nt * 16 + l15) * 72 + quad * 8];
            const short8 bb1 = *(const short8*)&sHT2[(nt * 16 + l15) * 72 + 32 + quad * 8];
            f32x4 t = MFMA16(a0, bb0, zero);
            c[nt] = MFMA16(a1, bb1, t);
        }
#pragma unroll
        for (int nt = 0; nt < 4; ++nt)
#pragma unroll
            for (int r = 0; r < 4; ++r) {
                const float v = fmaxf(c[nt][r] + hb2v[nt], 0.0f);
                sA1[(crow0 + r) * 72 + nt * 16 + l15] = f2b(v);
            }
    }

    // ---- L5: V(64) @ H3 -> 3, +hb3, sigmoid -> rgb ----
    {
        const short8 a0 = *(const short8*)&sA1[arow * 72 + quad * 8];
        const short8 a1 = *(const short8*)&sA1[arow * 72 + 32 + quad * 8];
        const short8 bb0 = *(const short8*)&sHT3[l15 * 72 + quad * 8];
        const short8 bb1 = *(const short8*)&sHT3[l15 * 72 + 32 + quad * 8];
        f32x4 c = MFMA16(a0, bb0, zero);
        c = MFMA16(a1, bb1, c);
        if (l15 < 3) {
#pragma unroll
            for (int r = 0; r < 4; ++r) {
                rgb_out[3 * (p0 + crow0 + r) + l15] = sigmoidf(c[r] + hb3v);
            }
        }
    }
}

// k3: one 64-thread block per batch. Softmax over S=48, weighted rgb sum.
__global__ __launch_bounds__(64) void reduce_kernel(
    const float* __restrict__ densities,
    const float* __restrict__ rgb,
    float* __restrict__ out)
{
    const int b = blockIdx.x;
    const int t = threadIdx.x;
    const bool valid = t < NS;

    float d = valid ? densities[b * NS + t] : -INFINITY;
    float m = d;
#pragma unroll
    for (int off = 32; off > 0; off >>= 1) m = fmaxf(m, __shfl_xor(m, off));
    float e = valid ? expf(d - m) : 0.0f;
    float sum = e;
#pragma unroll
    for (int off = 32; off > 0; off >>= 1) sum += __shfl_xor(sum, off);
    const float w = e / sum;

    float r0 = 0.0f, r1 = 0.0f, r2 = 0.0f;
    if (valid) {
        const int base = (b * NS + t) * 3;
        r0 = w * rgb[base + 0];
        r1 = w * rgb[base + 1];
        r2 = w * rgb[base + 2];
    }
#pragma unroll
    for (int off = 32; off > 0; off >>= 1) {
        r0 += __shfl_xor(r0, off);
        r1 += __shfl_xor(r1, off);
        r2 += __shfl_xor(r2, off);
    }
    if (t == 0) {
        out[3 * b + 0] = r0;
        out[3 * b + 1] = r1;
        out[3 * b + 2] = r2;
    }
}

extern "C" void kernel_launch(void* const* d_in, const int* in_sizes, int n_in,
                              void* d_out, int out_size, void* d_ws, size_t ws_size,
                              hipStream_t stream) {
    const float* positions = (const float*)d_in[0];
    const float* densities = (const float*)d_in[1];
    const float* normals   = (const float*)d_in[2];
    const float* c2w       = (const float*)d_in[3];
    const float* table     = (const float*)d_in[4];
    const float* w1  = (const float*)d_in[5];
    const float* b1  = (const float*)d_in[6];
    const float* w2  = (const float*)d_in[7];
    const float* b2  = (const float*)d_in[8];
    const float* h1  = (const float*)d_in[9];
    const float* hb1 = (const float*)d_in[10];
    const float* h2  = (const float*)d_in[11];
    const float* hb2 = (const float*)d_in[12];
    const float* h3  = (const float*)d_in[13];
    const float* hb3 = (const float*)d_in[14];
    float* out = (float*)d_out;

    // ws layout: q (NPTS float4) | enc (NLEV*NPTS float2) | rgb (NPTS*3 f32)
    float4* q_ws   = (float4*)d_ws;
    float2* enc_ws = (float2*)((char*)d_ws + sizeof(float4) * NPTS);
    float*  rgb_ws = (float*)((char*)enc_ws + sizeof(float2) * NLEV * NPTS);

    Scales sc;
    const double growth = exp((log(2048.0) - log(16.0)) / 15.0);
    for (int i = 0; i < NLEV; ++i)
        sc.s[i] = (float)floor(16.0 * pow(growth, (double)i));

    const int threads = 256;
    const int pblocks = (NPTS + threads - 1) / threads;

    transform_kernel<<<pblocks, threads, 0, stream>>>(positions, c2w, q_ws);
    encode_kernel<<<dim3(pblocks, NLEV), threads, 0, stream>>>(q_ws, table, enc_ws, sc);
    mfma_mlp_kernel<<<NPTS / 64, threads, 0, stream>>>(
        enc_ws, normals, c2w,
        w1, b1, w2, b2, h1, hb1, h2, hb2, h3, hb3, rgb_ws);
    reduce_kernel<<<NB, 64, 0, stream>>>(densities, rgb_ws, out);
}

// Round 5
// 222.549 us; speedup vs baseline: 4.4956x; 1.1937x over previous
//
#include <hip/hip_runtime.h>
#include <math.h>
#include <stdint.h>

#define NLEV 16
#define TSIZE (1u << 19)
#define NB 4096
#define NS 48
#define NPTS (NB * NS)

typedef __attribute__((ext_vector_type(8))) short short8;
typedef __attribute__((ext_vector_type(4))) float f32x4;

struct Scales { float s[NLEV]; };

__device__ __forceinline__ uint32_t hash3(uint32_t x, uint32_t y, uint32_t z) {
    return (x ^ (y * 2654435761u) ^ (z * 805459861u)) & (TSIZE - 1u);
}

__device__ __forceinline__ float sigmoidf(float v) {
    return 1.0f / (1.0f + expf(-v));
}

// fp32 -> bf16 (round to nearest even), raw ushort bits
__device__ __forceinline__ ushort f2b(float f) {
    union { float f; uint32_t u; } v; v.f = f;
    uint32_t r = (v.u + 0x7FFFu + ((v.u >> 16) & 1u)) >> 16;
    return (ushort)r;
}

#define MFMA16(a, b, c) __builtin_amdgcn_mfma_f32_16x16x32_bf16((a), (b), (c), 0, 0, 0)

// Fragment bank: 20 B-fragments, each 64 lanes x 8 bf16 (1 KB), lane-ordered
// so a wave loads one fragment with a single coalesced dwordx4.
//   f0..3  : W1^T  n-tile 0..3          (L1, k=quad*8+j)
//   f4..5  : W2^T  k-half 0..1          (L2)
//   f6..9  : H1^T  n-tile 0..3          (L3)
//   f10..17: H2^T  (nt,kk) = (f-10)>>1, (f-10)&1   (L4)
//   f18..19: H3^T  k-half 0..1 (cols>=3 zero)      (L5)
__global__ __launch_bounds__(256) void prep_kernel(
    const float* __restrict__ w1, const float* __restrict__ w2,
    const float* __restrict__ h1, const float* __restrict__ h2,
    const float* __restrict__ h3,
    ushort* __restrict__ bank)
{
    for (int idx = threadIdx.x; idx < 20 * 512; idx += 256) {
        const int f    = idx >> 9;
        const int r    = idx & 511;
        const int lane = r >> 3;
        const int j    = r & 7;
        const int l15  = lane & 15;
        const int quad = lane >> 4;
        const int k8   = quad * 8 + j;   // 0..31
        float val;
        if (f < 4) {
            val = w1[k8 * 64 + f * 16 + l15];
        } else if (f < 6) {
            val = w2[((f - 4) * 32 + k8) * 16 + l15];
        } else if (f < 10) {
            val = h1[k8 * 64 + (f - 6) * 16 + l15];
        } else if (f < 18) {
            const int t = f - 10, nt = t >> 1, kk = t & 1;
            val = h2[(kk * 32 + k8) * 64 + nt * 16 + l15];
        } else {
            val = (l15 < 3) ? h3[((f - 18) * 32 + k8) * 3 + l15] : 0.0f;
        }
        bank[idx] = f2b(val);
    }
}

// k1: fused transform+encode. One thread per (point, level); recomputes the
// camera transform per level (trivial VALU vs gather latency). Writes enc as
// packed bf16 pair (uint32) to level-major enc_ws[l][p].
__global__ __launch_bounds__(256) void encode_kernel(
    const float* __restrict__ positions,
    const float* __restrict__ c2w,
    const float* __restrict__ table,
    uint32_t* __restrict__ enc_ws,
    Scales sc)
{
    const int p = blockIdx.x * blockDim.x + threadIdx.x;
    if (p >= NPTS) return;
    const int l = blockIdx.y;
    const int b = p / NS;

    const float* M = c2w + b * 12;
    const float px = positions[3 * p + 0];
    const float py = positions[3 * p + 1];
    const float pz = positions[3 * p + 2];
    const float dx = px - M[3], dy = py - M[7], dz = pz - M[11];
    float qx = M[0] * dx + M[4] * dy + M[8] * dz;
    float qy = M[1] * dx + M[5] * dy + M[9] * dz;
    float qz = M[2] * dx + M[6] * dy + M[10] * dz;
    qx = (qx + 1.0f) * 0.5f;
    qy = (qy + 1.0f) * 0.5f;
    qz = (qz + 1.0f) * 0.5f;
    const bool sel = (qx > 0.0f) && (qx < 1.0f) &&
                     (qy > 0.0f) && (qy < 1.0f) &&
                     (qz > 0.0f) && (qz < 1.0f);
    if (!sel) { qx = 0.0f; qy = 0.0f; qz = 0.0f; }

    const float s = sc.s[l];
    const float sx = qx * s, sy = qy * s, sz = qz * s;
    const float fx = floorf(sx), fy = floorf(sy), fz = floorf(sz);
    const float cx = ceilf(sx),  cy = ceilf(sy),  cz = ceilf(sz);
    const float ox = sx - fx, oy = sy - fy, oz = sz - fz;
    const uint32_t fxi = (uint32_t)fx, fyi = (uint32_t)fy, fzi = (uint32_t)fz;
    const uint32_t cxi = (uint32_t)cx, cyi = (uint32_t)cy, czi = (uint32_t)cz;

    const float2* tab2 = (const float2*)table + (uint32_t)l * TSIZE;
    const float2 f0 = tab2[hash3(cxi, cyi, czi)];
    const float2 f1 = tab2[hash3(cxi, fyi, czi)];
    const float2 f2 = tab2[hash3(fxi, fyi, czi)];
    const float2 f3 = tab2[hash3(fxi, cyi, czi)];
    const float2 f4 = tab2[hash3(cxi, cyi, fzi)];
    const float2 f5 = tab2[hash3(cxi, fyi, fzi)];
    const float2 f6 = tab2[hash3(fxi, fyi, fzi)];
    const float2 f7 = tab2[hash3(fxi, cyi, fzi)];

    const float omx = 1.0f - ox, omy = 1.0f - oy, omz = 1.0f - oz;
    float f03x = f0.x * ox + f3.x * omx, f03y = f0.y * ox + f3.y * omx;
    float f12x = f1.x * ox + f2.x * omx, f12y = f1.y * ox + f2.y * omx;
    float f56x = f5.x * ox + f6.x * omx, f56y = f5.y * ox + f6.y * omx;
    float f47x = f4.x * ox + f7.x * omx, f47y = f4.y * ox + f7.y * omx;
    float ax = f03x * oy + f12x * omy, ay = f03y * oy + f12y * omy;
    float bx = f47x * oy + f56x * omy, by = f47y * oy + f56y * omy;
    const float ex = ax * oz + bx * omz;
    const float ey = ay * oz + by * omz;
    enc_ws[l * NPTS + p] = ((uint32_t)f2b(ey) << 16) | (uint32_t)f2b(ex);
}

// k2: MFMA MLP. One block = 64 points, 4 waves; each wave owns a 16-point
// m-tile. Layers chained through LDS in bf16 (fp32 accumulate). B-fragments
// come straight from the prep bank (one coalesced dwordx4 per fragment, L2
// hot) — weights never touch LDS. Fragment layouts (verified, m89/m120):
//   A: [m=lane&15][k=quad*8+j]   B: [n=lane&15][k=quad*8+j]
//   C/D: col=lane&15, row=quad*4+reg
__global__ __launch_bounds__(256) void mfma_mlp_kernel(
    const uint32_t* __restrict__ enc_ws,
    const float* __restrict__ normals,
    const float* __restrict__ c2w,
    const ushort* __restrict__ bank,
    const float* __restrict__ b1, const float* __restrict__ b2,
    const float* __restrict__ hb1, const float* __restrict__ hb2,
    const float* __restrict__ hb3,
    float* __restrict__ rgb_out)
{
    __shared__ ushort sX[64 * 40];    // L1 input  (32 feats + pad)
    __shared__ ushort sA1[64 * 72];   // L1 output (64); reused as V (L4 out)
    __shared__ ushort sHIN[64 * 40];  // [SH16 | geo16] (+ pad)
    __shared__ ushort sU[64 * 72];    // L3 output (64)

    const int tid = threadIdx.x;
    const int p0  = blockIdx.x * 64;

    // ---- stage X: enc (level-major packed bf16) -> [point][32] ----
    {
        const int pt = tid & 63;
        const int l0 = (tid >> 6) * 4;
        const int p  = p0 + pt;
#pragma unroll
        for (int l = l0; l < l0 + 4; ++l) {
            *(uint32_t*)&sX[pt * 40 + 2 * l] = enc_ws[l * NPTS + p];
        }
    }

    // ---- stage SH16 into sHIN[:, 0:16] ----
    if (tid < 64) {
        const int p = p0 + tid;
        const int b = p / NS;
        const float* M = c2w + b * 12;
        const float n0 = normals[3 * b + 0];
        const float n1 = normals[3 * b + 1];
        const float n2 = normals[3 * b + 2];
        float x = M[0] * n0 + M[4] * n1 + M[8] * n2;
        float y = M[1] * n0 + M[5] * n1 + M[9] * n2;
        float z = M[2] * n0 + M[6] * n1 + M[10] * n2;
        x = (x + 1.0f) * 0.5f;
        y = (y + 1.0f) * 0.5f;
        z = (z + 1.0f) * 0.5f;
        const float xx = x * x, yy = y * y, zz = z * z;
        float sh[16];
        sh[0]  = 0.28209479177387814f;
        sh[1]  = -0.48860251190291987f * y;
        sh[2]  = 0.48860251190291987f * z;
        sh[3]  = -0.48860251190291987f * x;
        sh[4]  = 1.0925484305920792f * x * y;
        sh[5]  = -1.0925484305920792f * y * z;
        sh[6]  = 0.94617469575756f * zz - 0.31539156525252f;
        sh[7]  = -1.0925484305920792f * x * z;
        sh[8]  = 0.5462742152960396f * (xx - yy);
        sh[9]  = 0.5900435899266435f * y * (3.0f * xx - yy);
        sh[10] = 2.890611442640554f * x * y * z;
        sh[11] = 0.4570457994644657f * y * (5.0f * zz - 1.0f);
        sh[12] = 0.37317633259011546f * z * (5.0f * zz - 3.0f);
        sh[13] = 0.4570457994644657f * x * (5.0f * zz - 1.0f);
        sh[14] = 1.445305721320277f * z * (xx - yy);
        sh[15] = 0.5900435899266435f * x * (xx - 3.0f * yy);
#pragma unroll
        for (int i = 0; i < 16; ++i) sHIN[tid * 40 + i] = f2b(sh[i]);
    }

    const int lane = tid & 63;
    const int wv   = tid >> 6;
    const int l15  = lane & 15;
    const int quad = lane >> 4;
    float b1v[4], hb1v[4], hb2v[4];
#pragma unroll
    for (int nt = 0; nt < 4; ++nt) {
        b1v[nt]  = b1[nt * 16 + l15];
        hb1v[nt] = hb1[nt * 16 + l15];
        hb2v[nt] = hb2[nt * 16 + l15];
    }
    const float b2v  = b2[l15];
    const float hb3v = (l15 < 3) ? hb3[l15] : 0.0f;

    const ushort* fb = bank + lane * 8;  // this lane's slot in each fragment
#define FRAG(f) (*(const short8*)(fb + (f) * 512))

    __syncthreads();
    // All inter-layer deps below are intra-wave (each wave touches only its
    // own 16 rows); per-wave in-order DS handles RAW/WAR without barriers.

    const int arow  = wv * 16 + l15;        // A-operand row (point in block)
    const int crow0 = wv * 16 + quad * 4;   // C-layout base row
    const f32x4 zero = {0.0f, 0.0f, 0.0f, 0.0f};

    // ---- L1: X(32) @ W1 -> 64, +b1, relu -> sA1 ----
    {
        const short8 a = *(const short8*)&sX[arow * 40 + quad * 8];
        f32x4 c[4];
#pragma unroll
        for (int nt = 0; nt < 4; ++nt) c[nt] = MFMA16(a, FRAG(nt), zero);
#pragma unroll
        for (int nt = 0; nt < 4; ++nt)
#pragma unroll
            for (int r = 0; r < 4; ++r) {
                const float v = fmaxf(c[nt][r] + b1v[nt], 0.0f);
                sA1[(crow0 + r) * 72 + nt * 16 + l15] = f2b(v);
            }
    }

    // ---- L2: A1(64) @ W2 -> 16 geo, +b2, relu -> sHIN[:,16:32] ----
    {
        const short8 a0 = *(const short8*)&sA1[arow * 72 + quad * 8];
        const short8 a1 = *(const short8*)&sA1[arow * 72 + 32 + quad * 8];
        f32x4 c = MFMA16(a0, FRAG(4), zero);
        c = MFMA16(a1, FRAG(5), c);
#pragma unroll
        for (int r = 0; r < 4; ++r) {
            const float v = fmaxf(c[r] + b2v, 0.0f);
            sHIN[(crow0 + r) * 40 + 16 + l15] = f2b(v);
        }
    }

    // ---- L3: HIN(32) @ H1 -> 64, +hb1, relu -> sU ----
    {
        const short8 a = *(const short8*)&sHIN[arow * 40 + quad * 8];
        f32x4 c[4];
#pragma unroll
        for (int nt = 0; nt < 4; ++nt) c[nt] = MFMA16(a, FRAG(6 + nt), zero);
#pragma unroll
        for (int nt = 0; nt < 4; ++nt)
#pragma unroll
            for (int r = 0; r < 4; ++r) {
                const float v = fmaxf(c[nt][r] + hb1v[nt], 0.0f);
                sU[(crow0 + r) * 72 + nt * 16 + l15] = f2b(v);
            }
    }

    // ---- L4: U(64) @ H2 -> 64, +hb2, relu -> sA1 (reused as V) ----
    {
        const short8 a0 = *(const short8*)&sU[arow * 72 + quad * 8];
        const short8 a1 = *(const short8*)&sU[arow * 72 + 32 + quad * 8];
        f32x4 c[4];
#pragma unroll
        for (int nt = 0; nt < 4; ++nt) {
            f32x4 t = MFMA16(a0, FRAG(10 + nt * 2), zero);
            c[nt] = MFMA16(a1, FRAG(11 + nt * 2), t);
        }
#pragma unroll
        for (int nt = 0; nt < 4; ++nt)
#pragma unroll
            for (int r = 0; r < 4; ++r) {
                const float v = fmaxf(c[nt][r] + hb2v[nt], 0.0f);
                sA1[(crow0 + r) * 72 + nt * 16 + l15] = f2b(v);
            }
    }

    // ---- L5: V(64) @ H3 -> 3, +hb3, sigmoid -> rgb ----
    {
        const short8 a0 = *(const short8*)&sA1[arow * 72 + quad * 8];
        const short8 a1 = *(const short8*)&sA1[arow * 72 + 32 + quad * 8];
        f32x4 c = MFMA16(a0, FRAG(18), zero);
        c = MFMA16(a1, FRAG(19), c);
        if (l15 < 3) {
#pragma unroll
            for (int r = 0; r < 4; ++r) {
                rgb_out[3 * (p0 + crow0 + r) + l15] = sigmoidf(c[r] + hb3v);
            }
        }
    }
#undef FRAG
}

// k3: one 64-thread block per batch. Softmax over S=48, weighted rgb sum.
__global__ __launch_bounds__(64) void reduce_kernel(
    const float* __restrict__ densities,
    const float* __restrict__ rgb,
    float* __restrict__ out)
{
    const int b = blockIdx.x;
    const int t = threadIdx.x;
    const bool valid = t < NS;

    float d = valid ? densities[b * NS + t] : -INFINITY;
    float m = d;
#pragma unroll
    for (int off = 32; off > 0; off >>= 1) m = fmaxf(m, __shfl_xor(m, off));
    float e = valid ? expf(d - m) : 0.0f;
    float sum = e;
#pragma unroll
    for (int off = 32; off > 0; off >>= 1) sum += __shfl_xor(sum, off);
    const float w = e / sum;

    float r0 = 0.0f, r1 = 0.0f, r2 = 0.0f;
    if (valid) {
        const int base = (b * NS + t) * 3;
        r0 = w * rgb[base + 0];
        r1 = w * rgb[base + 1];
        r2 = w * rgb[base + 2];
    }
#pragma unroll
    for (int off = 32; off > 0; off >>= 1) {
        r0 += __shfl_xor(r0, off);
        r1 += __shfl_xor(r1, off);
        r2 += __shfl_xor(r2, off);
    }
    if (t == 0) {
        out[3 * b + 0] = r0;
        out[3 * b + 1] = r1;
        out[3 * b + 2] = r2;
    }
}

extern "C" void kernel_launch(void* const* d_in, const int* in_sizes, int n_in,
                              void* d_out, int out_size, void* d_ws, size_t ws_size,
                              hipStream_t stream) {
    const float* positions = (const float*)d_in[0];
    const float* densities = (const float*)d_in[1];
    const float* normals   = (const float*)d_in[2];
    const float* c2w       = (const float*)d_in[3];
    const float* table     = (const float*)d_in[4];
    const float* w1  = (const float*)d_in[5];
    const float* b1  = (const float*)d_in[6];
    const float* w2  = (const float*)d_in[7];
    const float* b2  = (const float*)d_in[8];
    const float* h1  = (const float*)d_in[9];
    const float* hb1 = (const float*)d_in[10];
    const float* h2  = (const float*)d_in[11];
    const float* hb2 = (const float*)d_in[12];
    const float* h3  = (const float*)d_in[13];
    const float* hb3 = (const float*)d_in[14];
    float* out = (float*)d_out;

    // ws layout: bank (20KB) | enc (NLEV*NPTS u32) | rgb (NPTS*3 f32)
    ushort*   bank   = (ushort*)d_ws;
    uint32_t* enc_ws = (uint32_t*)((char*)d_ws + 20 * 1024);
    float*    rgb_ws = (float*)((char*)enc_ws + sizeof(uint32_t) * NLEV * NPTS);

    Scales sc;
    const double growth = exp((log(2048.0) - log(16.0)) / 15.0);
    for (int i = 0; i < NLEV; ++i)
        sc.s[i] = (float)floor(16.0 * pow(growth, (double)i));

    const int threads = 256;
    const int pblocks = NPTS / threads;

    prep_kernel<<<1, threads, 0, stream>>>(w1, w2, h1, h2, h3, bank);
    encode_kernel<<<dim3(pblocks, NLEV), threads, 0, stream>>>(
        positions, c2w, table, enc_ws, sc);
    mfma_mlp_kernel<<<NPTS / 64, threads, 0, stream>>>(
        enc_ws, normals, c2w, bank, b1, b2, hb1, hb2, hb3, rgb_ws);
    reduce_kernel<<<NB, 64, 0, stream>>>(densities, rgb_ws, out);
}